// Round 21
// baseline (83.994 us; speedup 1.0000x reference)
//
#include <hip/hip_runtime.h>
#include <hip/hip_bf16.h>
#include <cstdint>
#include <cstddef>

typedef __attribute__((ext_vector_type(8))) short bf16x8;
typedef __attribute__((ext_vector_type(4))) float f32x4;
typedef __attribute__((ext_vector_type(4))) unsigned int u32x4;

#define T_DIM 2048
#define C_DIM 1024
#define B_DIM 8
#define NEG_BIG (-3.0e38f)
#define QSCALE 0.18033688011112042f   // (1/8) * log2(e): softmax in exp2 domain

__device__ __forceinline__ unsigned short f2bf(float f) {
  union { __hip_bfloat16 h; unsigned short u; } cv;
  cv.h = __float2bfloat16(f);
  return cv.u;
}
__device__ __forceinline__ f32x4 mfma16(bf16x8 a, bf16x8 b, f32x4 c) {
  return __builtin_amdgcn_mfma_f32_16x16x32_bf16(a, b, c, 0, 0, 0);
}

// ---------------------------------------------------------------------------
// prep_w: W [1024][64] f32 -> Wt [3][64][1024] bf16 (transposed; Wq scaled by
// (1/8)*log2e so softmax runs in exp2 domain). Unchanged.
// ---------------------------------------------------------------------------
__global__ __launch_bounds__(256) void prep_w(
    const float* __restrict__ Wq, const float* __restrict__ Wk,
    const float* __restrict__ Wv, unsigned short* __restrict__ Wt)
{
  const int mtx = blockIdx.x >> 4;
  const int k0  = (blockIdx.x & 15) * 64;
  const float* W = (mtx == 0) ? Wq : ((mtx == 1) ? Wk : Wv);
  const float scale = (mtx == 0) ? QSCALE : 1.0f;
  __shared__ float Ws[64][65];
  const int t = threadIdx.x;
#pragma unroll
  for (int j = 0; j < 4; ++j) {
    int r = (t >> 4) + 16 * j;
    int c = (t & 15) * 4;
    union { float4 f4; float f[4]; } uv;
    uv.f4 = *(const float4*)&W[(size_t)(k0 + r) * 64 + c];
#pragma unroll
    for (int jj = 0; jj < 4; ++jj) Ws[c + jj][r] = uv.f[jj] * scale;
  }
  __syncthreads();
#pragma unroll
  for (int q = 0; q < 2; ++q) {
    int g_ = t + 256 * q;
    int d  = g_ >> 3;
    int ko = (g_ & 7) * 8;
    union { unsigned short u[8]; u32x4 v; } pk;
#pragma unroll
    for (int jj = 0; jj < 8; ++jj) pk.u[jj] = f2bf(Ws[d][ko + jj]);
    *(u32x4*)&Wt[((size_t)mtx * 64 + d) * C_DIM + k0 + ko] = pk.v;
  }
}

// ---------------------------------------------------------------------------
// qkv_proj_mfma v3: HIGH-TLP variant. Re-derived accounting (r19: proj ~28us,
// r18: MfmaUtil 6%, VALU 4%, HBM 9-14% => pure latency at 2 blocks/CU).
// Grid 1024 x 16 rows/block, LDS ~6KB => 6-8 blocks/CU (24-32 waves/CU):
// other blocks' compute covers each block's barrier drains.
//  - X staged COALESCED through LDS (r19 lesson: direct x gather = 3x loss),
//    double-buffered, one barrier per kt.
//  - W B-frags read DIRECTLY from L2-hot Wt (384 KB resident; same fragment
//    gather pattern as attn's K loads). No W LDS.
// Each of 4 waves: same 16 rows, 3 of 12 n-tiles. acc = 3 x f32x4.
// ---------------------------------------------------------------------------
__global__ __launch_bounds__(256) void qkv_proj_mfma(
    const float* __restrict__ x,
    const unsigned short* __restrict__ Wt,
    const float* __restrict__ bq, const float* __restrict__ bk, const float* __restrict__ bv,
    unsigned short* __restrict__ Qb, unsigned short* __restrict__ Kb,
    unsigned short* __restrict__ VTb)
{
  __shared__ __align__(16) short Xs[2][16 * 64];        // 2 KB each, swizzled
  __shared__ __align__(16) unsigned short VTs[64 * 24]; // V tile [64 d][16 t] pad 24

  const int tid = threadIdx.x;
  const int wv = tid >> 6, lane = tid & 63, g = lane >> 4, ln15 = lane & 15;
  const size_t m0 = (size_t)blockIdx.x * 16;

  f32x4 acc[3];
#pragma unroll
  for (int j = 0; j < 3; ++j) acc[j] = (f32x4){0.f, 0.f, 0.f, 0.f};

  // ---- coalesced X stage: 16 rows x 64 k f32 = 256 float4 granules ----
  float4 xr_;
  auto issueX = [&](int kt) {
    if (kt >= 16) return;
    int r = tid >> 4, c4 = (tid & 15) * 4;
    xr_ = *(const float4*)&x[(m0 + r) * C_DIM + kt * 64 + c4];
  };
  auto writeX = [&](int nb) {
    int r = tid >> 4, c4 = (tid & 15) * 4;
    const float* f = (const float*)&xr_;
    union { unsigned short u[4]; unsigned long long ll; } pk;
#pragma unroll
    for (int jj = 0; jj < 4; ++jj) pk.u[jj] = f2bf(f[jj]);
    *(unsigned long long*)((char*)Xs[nb] + r * 128 + ((c4 * 2) ^ ((r & 7) << 4))) = pk.ll;
  };
  auto compute = [&](int nb, int kt) {
    bf16x8 a0, a1;
    {
      a0 = *(const bf16x8*)((const char*)Xs[nb] + ln15 * 128 + ((g * 16) ^ ((ln15 & 7) << 4)));
      a1 = *(const bf16x8*)((const char*)Xs[nb] + ln15 * 128 + ((64 + g * 16) ^ ((ln15 & 7) << 4)));
    }
#pragma unroll
    for (int j = 0; j < 3; ++j) {
      const unsigned short* wp = Wt + (size_t)((wv * 3 + j) * 16 + ln15) * C_DIM + kt * 64 + g * 8;
      bf16x8 b0 = *(const bf16x8*)wp;
      bf16x8 b1 = *(const bf16x8*)(wp + 32);
      acc[j] = mfma16(a0, b0, acc[j]);
      acc[j] = mfma16(a1, b1, acc[j]);
    }
  };

  issueX(0);
  writeX(0);
  issueX(1);
  __syncthreads();

  for (int kt = 0; kt < 16; ++kt) {
    const int cur = kt & 1;
    // next tile: regs already hold kt+1 (issued last phase); write to buf^1,
    // then issue kt+2 into regs. Compute current from buf cur + direct-L2 W.
    if (kt + 1 < 16) writeX(cur ^ 1);
    compute(cur, kt);
    issueX(kt + 2);
    __syncthreads();
  }

  // epilogue: Q/K direct; V (ntg 8..11) -> LDS tile -> coalesced VTb
#pragma unroll
  for (int j = 0; j < 3; ++j) {
    const int ntg = wv * 3 + j;
    const int mtx = ntg >> 2, nc = (ntg & 3) * 16;
    if (mtx < 2) {
      const float* bias = (mtx == 0) ? bq : bk;
      unsigned short* Out = (mtx == 0) ? Qb : Kb;
      float bvv = bias[nc + ln15] * ((mtx == 0) ? QSCALE : 1.0f);
#pragma unroll
      for (int i = 0; i < 4; ++i)
        Out[(m0 + 4 * g + i) * 64 + nc + ln15] = f2bf(acc[j][i] + bvv);
    } else {
      float bvv = bv[nc + ln15];
#pragma unroll
      for (int i = 0; i < 4; ++i)
        VTs[(nc + ln15) * 24 + 4 * g + i] = f2bf(acc[j][i] + bvv);
    }
  }
  __syncthreads();
  {
    // 64 d-rows x 16 t-cols: 128 threads write b128 (8 t each)
    if (tid < 128) {
      int d = tid >> 1, t8 = (tid & 1) * 8;
      u32x4 v0 = *(const u32x4*)&VTs[d * 24 + t8];
      size_t b = m0 >> 11, tloc = m0 & 2047;
      *(u32x4*)&VTb[(b * 64 + d) * T_DIM + tloc + t8] = v0;
    }
  }
}

// ---------------------------------------------------------------------------
// attn_flash: round-15 version EXACT (best measured). Unchanged.
// ---------------------------------------------------------------------------
__global__ __launch_bounds__(256, 2) void attn_flash(
    const unsigned short* __restrict__ Qb,   // [B*T][64] (pre-scaled QSCALE)
    const unsigned short* __restrict__ Kb,   // [B*T][64]
    const unsigned short* __restrict__ VTb,  // [B][64][T]
    float* __restrict__ out)                 // [B*T][64] f32
{
  __shared__ __align__(16) short Ps[4][2 * 16 * 64];
  __shared__ __align__(16) float Zs[3][2][16 * 68];
  __shared__ float Ml[3][2][16][2];

  const int tid  = threadIdx.x;
  const int wv   = tid >> 6;
  const int lane = tid & 63;
  const int g    = lane >> 4;
  const int ln15 = lane & 15;

  const int qt = 63 - (blockIdx.x >> 3);
  const int b  = blockIdx.x & 7;
  const int r0 = qt * 32;
  const int ntiles = (qt >> 1) + 1;

  const size_t bT = (size_t)b * T_DIM;

  bf16x8 qa[2][2];
#pragma unroll
  for (int mt = 0; mt < 2; ++mt) {
    const unsigned short* qp = Qb + (bT + r0 + mt * 16 + ln15) * 64 + g * 8;
    qa[mt][0] = *(const bf16x8*)qp;
    qa[mt][1] = *(const bf16x8*)(qp + 32);
  }

  f32x4 acc[2][4];
#pragma unroll
  for (int mt = 0; mt < 2; ++mt)
#pragma unroll
    for (int dt = 0; dt < 4; ++dt) acc[mt][dt] = (f32x4){0.f, 0.f, 0.f, 0.f};
  float m_[2], l_[2];
#pragma unroll
  for (int mt = 0; mt < 2; ++mt) { m_[mt] = NEG_BIG; l_[mt] = 0.f; }

  char* myP = (char*)Ps[wv];

  for (int it = wv; it < ntiles; it += 4) {
    const int s0 = it * 64;
    bf16x8 kf[4][2];
#pragma unroll
    for (int nt = 0; nt < 4; ++nt) {
      const unsigned short* kp = Kb + (bT + s0 + nt * 16 + ln15) * 64 + g * 8;
      kf[nt][0] = *(const bf16x8*)kp;
      kf[nt][1] = *(const bf16x8*)(kp + 32);
    }
    bf16x8 vf[4][2];
#pragma unroll
    for (int dt = 0; dt < 4; ++dt) {
      const unsigned short* vp = VTb + ((size_t)b * 64 + dt * 16 + ln15) * T_DIM + s0 + g * 8;
      vf[dt][0] = *(const bf16x8*)vp;
      vf[dt][1] = *(const bf16x8*)(vp + 32);
    }
    f32x4 st[2][4];
    __builtin_amdgcn_s_setprio(1);
#pragma unroll
    for (int mt = 0; mt < 2; ++mt)
#pragma unroll
      for (int nt = 0; nt < 4; ++nt) {
        f32x4 a = (f32x4){0.f, 0.f, 0.f, 0.f};
        a = mfma16(kf[nt][0], qa[mt][0], a);
        a = mfma16(kf[nt][1], qa[mt][1], a);
        st[mt][nt] = a;
      }
    __builtin_amdgcn_s_setprio(0);
    if (s0 + 63 > r0) {
#pragma unroll
      for (int mt = 0; mt < 2; ++mt) {
        const int qg = r0 + mt * 16 + ln15;
#pragma unroll
        for (int nt = 0; nt < 4; ++nt) {
          const int kvb = s0 + nt * 16 + 4 * g;
#pragma unroll
          for (int i = 0; i < 4; ++i)
            if (kvb + i > qg) st[mt][nt][i] = NEG_BIG;
        }
      }
    }
#pragma unroll
    for (int mt = 0; mt < 2; ++mt) {
      f32x4 t4;
#pragma unroll
      for (int i = 0; i < 4; ++i)
        t4[i] = fmaxf(fmaxf(st[mt][0][i], st[mt][1][i]), fmaxf(st[mt][2][i], st[mt][3][i]));
      float mx = fmaxf(fmaxf(t4[0], t4[1]), fmaxf(t4[2], t4[3]));
      if (!__all((int)(mx <= m_[mt] + 8.0f))) {
        mx = fmaxf(mx, __shfl_xor(mx, 16));
        mx = fmaxf(mx, __shfl_xor(mx, 32));
        const float mn = fmaxf(m_[mt], mx);
        const float corr = exp2f(m_[mt] - mn);
        m_[mt] = mn;
        l_[mt] *= corr;
#pragma unroll
        for (int dt = 0; dt < 4; ++dt)
#pragma unroll
          for (int i = 0; i < 4; ++i)
            acc[mt][dt][i] *= corr;
      }
#pragma unroll
      for (int nt = 0; nt < 4; ++nt)
#pragma unroll
        for (int i = 0; i < 4; ++i)
          st[mt][nt][i] = exp2f(st[mt][nt][i] - m_[mt]);
      float ps = 0.f;
#pragma unroll
      for (int nt = 0; nt < 4; ++nt)
        ps += (st[mt][nt][0] + st[mt][nt][1]) + (st[mt][nt][2] + st[mt][nt][3]);
      l_[mt] += ps;
#pragma unroll
      for (int nt = 0; nt < 4; ++nt) {
        unsigned int lo_ = (unsigned int)f2bf(st[mt][nt][0]) | ((unsigned int)f2bf(st[mt][nt][1]) << 16);
        unsigned int hi_ = (unsigned int)f2bf(st[mt][nt][2]) | ((unsigned int)f2bf(st[mt][nt][3]) << 16);
        *(unsigned long long*)(myP + mt * 2048 + ln15 * 128 +
                               ((nt * 32 + g * 8) ^ ((ln15 & 7) << 4))) =
            ((unsigned long long)hi_ << 32) | lo_;
      }
    }
    bf16x8 pb[2][2];
#pragma unroll
    for (int mt = 0; mt < 2; ++mt)
#pragma unroll
      for (int kc = 0; kc < 2; ++kc)
        pb[mt][kc] = *(const bf16x8*)(myP + mt * 2048 + ln15 * 128 +
                                      ((kc * 64 + g * 16) ^ ((ln15 & 7) << 4)));
    __builtin_amdgcn_s_setprio(1);
#pragma unroll
    for (int mt = 0; mt < 2; ++mt)
#pragma unroll
      for (int dt = 0; dt < 4; ++dt) {
        acc[mt][dt] = mfma16(vf[dt][0], pb[mt][0], acc[mt][dt]);
        acc[mt][dt] = mfma16(vf[dt][1], pb[mt][1], acc[mt][dt]);
      }
    __builtin_amdgcn_s_setprio(0);
  }

#pragma unroll
  for (int mt = 0; mt < 2; ++mt) {
    l_[mt] += __shfl_xor(l_[mt], 16);
    l_[mt] += __shfl_xor(l_[mt], 32);
  }

  if (wv > 0) {
#pragma unroll
    for (int mt = 0; mt < 2; ++mt) {
#pragma unroll
      for (int dt = 0; dt < 4; ++dt)
        *(f32x4*)&Zs[wv - 1][mt][ln15 * 68 + dt * 16 + 4 * g] = acc[mt][dt];
      if (g == 0) {
        Ml[wv - 1][mt][ln15][0] = m_[mt];
        Ml[wv - 1][mt][ln15][1] = l_[mt];
      }
    }
  }
  __syncthreads();
  if (wv == 0) {
#pragma unroll
    for (int mt = 0; mt < 2; ++mt) {
      float mm = m_[mt];
#pragma unroll
      for (int w = 0; w < 3; ++w) mm = fmaxf(mm, Ml[w][mt][ln15][0]);
      const float e0 = exp2f(m_[mt] - mm);
      float lsum = l_[mt] * e0;
      float ew[3];
#pragma unroll
      for (int w = 0; w < 3; ++w) {
        ew[w] = exp2f(Ml[w][mt][ln15][0] - mm);
        lsum += Ml[w][mt][ln15][1] * ew[w];
      }
      const float inv = 1.0f / lsum;
      float* ob = out + (bT + r0 + mt * 16 + ln15) * 64;
#pragma unroll
      for (int dt = 0; dt < 4; ++dt) {
        f32x4 z;
#pragma unroll
        for (int i = 0; i < 4; ++i) {
          float zz = acc[mt][dt][i] * e0;
#pragma unroll
          for (int w = 0; w < 3; ++w)
            zz += Zs[w][mt][ln15 * 68 + dt * 16 + 4 * g + i] * ew[w];
          z[i] = zz * inv;
        }
        *(f32x4*)&ob[dt * 16 + 4 * g] = z;
      }
    }
  }
}

// ---------------------------------------------------------------------------
extern "C" void kernel_launch(void* const* d_in, const int* in_sizes, int n_in,
                              void* d_out, int out_size, void* d_ws, size_t ws_size,
                              hipStream_t stream)
{
  const float* x  = (const float*)d_in[0];
  const float* Wq = (const float*)d_in[1];
  const float* bq = (const float*)d_in[2];
  const float* Wk = (const float*)d_in[3];
  const float* bk = (const float*)d_in[4];
  const float* Wv = (const float*)d_in[5];
  const float* bv = (const float*)d_in[6];
  float* out = (float*)d_out;

  char* ws = (char*)d_ws;
  unsigned short* Wt  = (unsigned short*)(ws);                      // 384 KB
  unsigned short* Qb  = (unsigned short*)(ws + (1u << 19));         // 2 MB
  unsigned short* Kb  = (unsigned short*)(ws + (1u << 19) + (1u << 21));
  unsigned short* VTb = (unsigned short*)(ws + (1u << 19) + (2u << 21));

  prep_w<<<48, 256, 0, stream>>>(Wq, Wk, Wv, Wt);
  qkv_proj_mfma<<<1024, 256, 0, stream>>>(x, Wt, bq, bk, bv, Qb, Kb, VTb);
  attn_flash<<<512, 256, 0, stream>>>(Qb, Kb, VTb, out);
}

// Round 22
// 83.069 us; speedup vs baseline: 1.0111x; 1.0111x over previous
//
#include <hip/hip_runtime.h>
#include <hip/hip_bf16.h>
#include <cstdint>
#include <cstddef>

typedef __attribute__((ext_vector_type(8))) short bf16x8;
typedef __attribute__((ext_vector_type(4))) float f32x4;
typedef __attribute__((ext_vector_type(4))) unsigned int u32x4;

#define T_DIM 2048
#define C_DIM 1024
#define B_DIM 8
#define NEG_BIG (-3.0e38f)
#define QSCALE 0.18033688011112042f   // (1/8) * log2(e): softmax in exp2 domain

__device__ __forceinline__ unsigned short f2bf(float f) {
  union { __hip_bfloat16 h; unsigned short u; } cv;
  cv.h = __float2bfloat16(f);
  return cv.u;
}
__device__ __forceinline__ f32x4 mfma16(bf16x8 a, bf16x8 b, f32x4 c) {
  return __builtin_amdgcn_mfma_f32_16x16x32_bf16(a, b, c, 0, 0, 0);
}

// ---------------------------------------------------------------------------
// prep_w: W [1024][64] f32 -> Wt2 K-TILE-MAJOR: [16 kt][192 n][64 k] bf16
// (row stride 128 B => proj's W fragment loads are wave-coalesced, the r21
// diagnosis: 2 KB-stride rows scatter 16 lanes over 16 lines). Wq scaled by
// (1/8)*log2e (exp2-domain softmax). n = mtx*64 + d.
// ---------------------------------------------------------------------------
__global__ __launch_bounds__(256) void prep_w(
    const float* __restrict__ Wq, const float* __restrict__ Wk,
    const float* __restrict__ Wv, unsigned short* __restrict__ Wt)
{
  const int mtx = blockIdx.x >> 4;
  const int kt  = blockIdx.x & 15;
  const int k0  = kt * 64;
  const float* W = (mtx == 0) ? Wq : ((mtx == 1) ? Wk : Wv);
  const float scale = (mtx == 0) ? QSCALE : 1.0f;
  __shared__ float Ws[64][65];
  const int t = threadIdx.x;
#pragma unroll
  for (int j = 0; j < 4; ++j) {
    int r = (t >> 4) + 16 * j;          // k-local
    int c = (t & 15) * 4;               // n-local (d)
    union { float4 f4; float f[4]; } uv;
    uv.f4 = *(const float4*)&W[(size_t)(k0 + r) * 64 + c];
#pragma unroll
    for (int jj = 0; jj < 4; ++jj) Ws[c + jj][r] = uv.f[jj] * scale;
  }
  __syncthreads();
  unsigned short* base = Wt + ((size_t)kt * 192 + (size_t)mtx * 64) * 64;
#pragma unroll
  for (int q = 0; q < 2; ++q) {
    int g_ = t + 256 * q;
    int d  = g_ >> 3;                   // n-local
    int ko = (g_ & 7) * 8;              // k-local
    union { unsigned short u[8]; u32x4 v; } pk;
#pragma unroll
    for (int jj = 0; jj < 8; ++jj) pk.u[jj] = f2bf(Ws[d][ko + jj]);
    *(u32x4*)&base[(size_t)d * 64 + ko] = pk.v;
  }
}

// ---------------------------------------------------------------------------
// qkv_proj_mfma v4: r21's high-TLP shell (grid 1024 x 16 rows, ~6 KB LDS,
// 28%+ occupancy) with the diagnosed flaw fixed: W reads from the k-tile-
// major layout are wave-coalesced (row stride 128 B, same pattern as attn's
// K loads). X staged coalesced through LDS (dbuf, 1 barrier/kt).
// ---------------------------------------------------------------------------
__global__ __launch_bounds__(256) void qkv_proj_mfma(
    const float* __restrict__ x,
    const unsigned short* __restrict__ Wt,
    const float* __restrict__ bq, const float* __restrict__ bk, const float* __restrict__ bv,
    unsigned short* __restrict__ Qb, unsigned short* __restrict__ Kb,
    unsigned short* __restrict__ VTb)
{
  __shared__ __align__(16) short Xs[2][16 * 64];        // 2 KB each, swizzled
  __shared__ __align__(16) unsigned short VTs[64 * 24]; // V tile [64 d][16 t]

  const int tid = threadIdx.x;
  const int wv = tid >> 6, lane = tid & 63, g = lane >> 4, ln15 = lane & 15;
  const size_t m0 = (size_t)blockIdx.x * 16;

  f32x4 acc[3];
#pragma unroll
  for (int j = 0; j < 3; ++j) acc[j] = (f32x4){0.f, 0.f, 0.f, 0.f};

  float4 xr_;
  auto issueX = [&](int kt) {
    if (kt >= 16) return;
    int r = tid >> 4, c4 = (tid & 15) * 4;
    xr_ = *(const float4*)&x[(m0 + r) * C_DIM + kt * 64 + c4];
  };
  auto writeX = [&](int nb) {
    int r = tid >> 4, c4 = (tid & 15) * 4;
    const float* f = (const float*)&xr_;
    union { unsigned short u[4]; unsigned long long ll; } pk;
#pragma unroll
    for (int jj = 0; jj < 4; ++jj) pk.u[jj] = f2bf(f[jj]);
    *(unsigned long long*)((char*)Xs[nb] + r * 128 + ((c4 * 2) ^ ((r & 7) << 4))) = pk.ll;
  };
  auto compute = [&](int nb, int kt) {
    bf16x8 a0, a1;
    a0 = *(const bf16x8*)((const char*)Xs[nb] + ln15 * 128 + ((g * 16) ^ ((ln15 & 7) << 4)));
    a1 = *(const bf16x8*)((const char*)Xs[nb] + ln15 * 128 + ((64 + g * 16) ^ ((ln15 & 7) << 4)));
#pragma unroll
    for (int j = 0; j < 3; ++j) {
      // k-tile-major: row stride 128 B -> coalesced fragment load
      const unsigned short* wp = Wt + ((size_t)kt * 192 + (wv * 3 + j) * 16 + ln15) * 64 + g * 8;
      bf16x8 b0 = *(const bf16x8*)wp;
      bf16x8 b1 = *(const bf16x8*)(wp + 32);
      acc[j] = mfma16(a0, b0, acc[j]);
      acc[j] = mfma16(a1, b1, acc[j]);
    }
  };

  issueX(0);
  writeX(0);
  issueX(1);
  __syncthreads();

  for (int kt = 0; kt < 16; ++kt) {
    const int cur = kt & 1;
    if (kt + 1 < 16) writeX(cur ^ 1);
    compute(cur, kt);
    issueX(kt + 2);
    __syncthreads();
  }

  // epilogue: Q/K direct; V (ntg 8..11) -> LDS tile -> coalesced VTb
#pragma unroll
  for (int j = 0; j < 3; ++j) {
    const int ntg = wv * 3 + j;
    const int mtx = ntg >> 2, nc = (ntg & 3) * 16;
    if (mtx < 2) {
      const float* bias = (mtx == 0) ? bq : bk;
      unsigned short* Out = (mtx == 0) ? Qb : Kb;
      float bvv = bias[nc + ln15] * ((mtx == 0) ? QSCALE : 1.0f);
#pragma unroll
      for (int i = 0; i < 4; ++i)
        Out[(m0 + 4 * g + i) * 64 + nc + ln15] = f2bf(acc[j][i] + bvv);
    } else {
      float bvv = bv[nc + ln15];
#pragma unroll
      for (int i = 0; i < 4; ++i)
        VTs[(nc + ln15) * 24 + 4 * g + i] = f2bf(acc[j][i] + bvv);
    }
  }
  __syncthreads();
  {
    if (tid < 128) {
      int d = tid >> 1, t8 = (tid & 1) * 8;
      u32x4 v0 = *(const u32x4*)&VTs[d * 24 + t8];
      size_t b = m0 >> 11, tloc = m0 & 2047;
      *(u32x4*)&VTb[(b * 64 + d) * T_DIM + tloc + t8] = v0;
    }
  }
}

// ---------------------------------------------------------------------------
// attn_flash: round-15 version EXACT (best measured). Unchanged.
// ---------------------------------------------------------------------------
__global__ __launch_bounds__(256, 2) void attn_flash(
    const unsigned short* __restrict__ Qb,   // [B*T][64] (pre-scaled QSCALE)
    const unsigned short* __restrict__ Kb,   // [B*T][64]
    const unsigned short* __restrict__ VTb,  // [B][64][T]
    float* __restrict__ out)                 // [B*T][64] f32
{
  __shared__ __align__(16) short Ps[4][2 * 16 * 64];
  __shared__ __align__(16) float Zs[3][2][16 * 68];
  __shared__ float Ml[3][2][16][2];

  const int tid  = threadIdx.x;
  const int wv   = tid >> 6;
  const int lane = tid & 63;
  const int g    = lane >> 4;
  const int ln15 = lane & 15;

  const int qt = 63 - (blockIdx.x >> 3);
  const int b  = blockIdx.x & 7;
  const int r0 = qt * 32;
  const int ntiles = (qt >> 1) + 1;

  const size_t bT = (size_t)b * T_DIM;

  bf16x8 qa[2][2];
#pragma unroll
  for (int mt = 0; mt < 2; ++mt) {
    const unsigned short* qp = Qb + (bT + r0 + mt * 16 + ln15) * 64 + g * 8;
    qa[mt][0] = *(const bf16x8*)qp;
    qa[mt][1] = *(const bf16x8*)(qp + 32);
  }

  f32x4 acc[2][4];
#pragma unroll
  for (int mt = 0; mt < 2; ++mt)
#pragma unroll
    for (int dt = 0; dt < 4; ++dt) acc[mt][dt] = (f32x4){0.f, 0.f, 0.f, 0.f};
  float m_[2], l_[2];
#pragma unroll
  for (int mt = 0; mt < 2; ++mt) { m_[mt] = NEG_BIG; l_[mt] = 0.f; }

  char* myP = (char*)Ps[wv];

  for (int it = wv; it < ntiles; it += 4) {
    const int s0 = it * 64;
    bf16x8 kf[4][2];
#pragma unroll
    for (int nt = 0; nt < 4; ++nt) {
      const unsigned short* kp = Kb + (bT + s0 + nt * 16 + ln15) * 64 + g * 8;
      kf[nt][0] = *(const bf16x8*)kp;
      kf[nt][1] = *(const bf16x8*)(kp + 32);
    }
    bf16x8 vf[4][2];
#pragma unroll
    for (int dt = 0; dt < 4; ++dt) {
      const unsigned short* vp = VTb + ((size_t)b * 64 + dt * 16 + ln15) * T_DIM + s0 + g * 8;
      vf[dt][0] = *(const bf16x8*)vp;
      vf[dt][1] = *(const bf16x8*)(vp + 32);
    }
    f32x4 st[2][4];
    __builtin_amdgcn_s_setprio(1);
#pragma unroll
    for (int mt = 0; mt < 2; ++mt)
#pragma unroll
      for (int nt = 0; nt < 4; ++nt) {
        f32x4 a = (f32x4){0.f, 0.f, 0.f, 0.f};
        a = mfma16(kf[nt][0], qa[mt][0], a);
        a = mfma16(kf[nt][1], qa[mt][1], a);
        st[mt][nt] = a;
      }
    __builtin_amdgcn_s_setprio(0);
    if (s0 + 63 > r0) {
#pragma unroll
      for (int mt = 0; mt < 2; ++mt) {
        const int qg = r0 + mt * 16 + ln15;
#pragma unroll
        for (int nt = 0; nt < 4; ++nt) {
          const int kvb = s0 + nt * 16 + 4 * g;
#pragma unroll
          for (int i = 0; i < 4; ++i)
            if (kvb + i > qg) st[mt][nt][i] = NEG_BIG;
        }
      }
    }
#pragma unroll
    for (int mt = 0; mt < 2; ++mt) {
      f32x4 t4;
#pragma unroll
      for (int i = 0; i < 4; ++i)
        t4[i] = fmaxf(fmaxf(st[mt][0][i], st[mt][1][i]), fmaxf(st[mt][2][i], st[mt][3][i]));
      float mx = fmaxf(fmaxf(t4[0], t4[1]), fmaxf(t4[2], t4[3]));
      if (!__all((int)(mx <= m_[mt] + 8.0f))) {
        mx = fmaxf(mx, __shfl_xor(mx, 16));
        mx = fmaxf(mx, __shfl_xor(mx, 32));
        const float mn = fmaxf(m_[mt], mx);
        const float corr = exp2f(m_[mt] - mn);
        m_[mt] = mn;
        l_[mt] *= corr;
#pragma unroll
        for (int dt = 0; dt < 4; ++dt)
#pragma unroll
          for (int i = 0; i < 4; ++i)
            acc[mt][dt][i] *= corr;
      }
#pragma unroll
      for (int nt = 0; nt < 4; ++nt)
#pragma unroll
        for (int i = 0; i < 4; ++i)
          st[mt][nt][i] = exp2f(st[mt][nt][i] - m_[mt]);
      float ps = 0.f;
#pragma unroll
      for (int nt = 0; nt < 4; ++nt)
        ps += (st[mt][nt][0] + st[mt][nt][1]) + (st[mt][nt][2] + st[mt][nt][3]);
      l_[mt] += ps;
#pragma unroll
      for (int nt = 0; nt < 4; ++nt) {
        unsigned int lo_ = (unsigned int)f2bf(st[mt][nt][0]) | ((unsigned int)f2bf(st[mt][nt][1]) << 16);
        unsigned int hi_ = (unsigned int)f2bf(st[mt][nt][2]) | ((unsigned int)f2bf(st[mt][nt][3]) << 16);
        *(unsigned long long*)(myP + mt * 2048 + ln15 * 128 +
                               ((nt * 32 + g * 8) ^ ((ln15 & 7) << 4))) =
            ((unsigned long long)hi_ << 32) | lo_;
      }
    }
    bf16x8 pb[2][2];
#pragma unroll
    for (int mt = 0; mt < 2; ++mt)
#pragma unroll
      for (int kc = 0; kc < 2; ++kc)
        pb[mt][kc] = *(const bf16x8*)(myP + mt * 2048 + ln15 * 128 +
                                      ((kc * 64 + g * 16) ^ ((ln15 & 7) << 4)));
    __builtin_amdgcn_s_setprio(1);
#pragma unroll
    for (int mt = 0; mt < 2; ++mt)
#pragma unroll
      for (int dt = 0; dt < 4; ++dt) {
        acc[mt][dt] = mfma16(vf[dt][0], pb[mt][0], acc[mt][dt]);
        acc[mt][dt] = mfma16(vf[dt][1], pb[mt][1], acc[mt][dt]);
      }
    __builtin_amdgcn_s_setprio(0);
  }

#pragma unroll
  for (int mt = 0; mt < 2; ++mt) {
    l_[mt] += __shfl_xor(l_[mt], 16);
    l_[mt] += __shfl_xor(l_[mt], 32);
  }

  if (wv > 0) {
#pragma unroll
    for (int mt = 0; mt < 2; ++mt) {
#pragma unroll
      for (int dt = 0; dt < 4; ++dt)
        *(f32x4*)&Zs[wv - 1][mt][ln15 * 68 + dt * 16 + 4 * g] = acc[mt][dt];
      if (g == 0) {
        Ml[wv - 1][mt][ln15][0] = m_[mt];
        Ml[wv - 1][mt][ln15][1] = l_[mt];
      }
    }
  }
  __syncthreads();
  if (wv == 0) {
#pragma unroll
    for (int mt = 0; mt < 2; ++mt) {
      float mm = m_[mt];
#pragma unroll
      for (int w = 0; w < 3; ++w) mm = fmaxf(mm, Ml[w][mt][ln15][0]);
      const float e0 = exp2f(m_[mt] - mm);
      float lsum = l_[mt] * e0;
      float ew[3];
#pragma unroll
      for (int w = 0; w < 3; ++w) {
        ew[w] = exp2f(Ml[w][mt][ln15][0] - mm);
        lsum += Ml[w][mt][ln15][1] * ew[w];
      }
      const float inv = 1.0f / lsum;
      float* ob = out + (bT + r0 + mt * 16 + ln15) * 64;
#pragma unroll
      for (int dt = 0; dt < 4; ++dt) {
        f32x4 z;
#pragma unroll
        for (int i = 0; i < 4; ++i) {
          float zz = acc[mt][dt][i] * e0;
#pragma unroll
          for (int w = 0; w < 3; ++w)
            zz += Zs[w][mt][ln15 * 68 + dt * 16 + 4 * g + i] * ew[w];
          z[i] = zz * inv;
        }
        *(f32x4*)&ob[dt * 16 + 4 * g] = z;
      }
    }
  }
}

// ---------------------------------------------------------------------------
extern "C" void kernel_launch(void* const* d_in, const int* in_sizes, int n_in,
                              void* d_out, int out_size, void* d_ws, size_t ws_size,
                              hipStream_t stream)
{
  const float* x  = (const float*)d_in[0];
  const float* Wq = (const float*)d_in[1];
  const float* bq = (const float*)d_in[2];
  const float* Wk = (const float*)d_in[3];
  const float* bk = (const float*)d_in[4];
  const float* Wv = (const float*)d_in[5];
  const float* bv = (const float*)d_in[6];
  float* out = (float*)d_out;

  char* ws = (char*)d_ws;
  unsigned short* Wt  = (unsigned short*)(ws);                      // 384 KB
  unsigned short* Qb  = (unsigned short*)(ws + (1u << 19));         // 2 MB
  unsigned short* Kb  = (unsigned short*)(ws + (1u << 19) + (1u << 21));
  unsigned short* VTb = (unsigned short*)(ws + (1u << 19) + (2u << 21));

  prep_w<<<48, 256, 0, stream>>>(Wq, Wk, Wv, Wt);
  qkv_proj_mfma<<<1024, 256, 0, stream>>>(x, Wt, bq, bk, bv, Qb, Kb, VTb);
  attn_flash<<<512, 256, 0, stream>>>(Qb, Kb, VTb, out);
}

// Round 23
// 57.752 us; speedup vs baseline: 1.4544x; 1.4384x over previous
//
#include <hip/hip_runtime.h>
#include <hip/hip_bf16.h>
#include <cstdint>
#include <cstddef>

typedef __attribute__((ext_vector_type(8))) short bf16x8;
typedef __attribute__((ext_vector_type(4))) float f32x4;
typedef __attribute__((ext_vector_type(4))) unsigned int u32x4;

#define T_DIM 2048
#define C_DIM 1024
#define B_DIM 8
#define NEG_BIG (-3.0e38f)
#define QSCALE 0.18033688011112042f   // (1/8) * log2(e): softmax in exp2 domain

__device__ __forceinline__ unsigned short f2bf(float f) {
  union { __hip_bfloat16 h; unsigned short u; } cv;
  cv.h = __float2bfloat16(f);
  return cv.u;
}
__device__ __forceinline__ f32x4 mfma16(bf16x8 a, bf16x8 b, f32x4 c) {
  return __builtin_amdgcn_mfma_f32_16x16x32_bf16(a, b, c, 0, 0, 0);
}

// ---------------------------------------------------------------------------
// prep_w: W [1024][64] f32 -> Wt [3*64 n][1024 k] bf16 (k-major rows; Wq
// scaled by (1/8)*log2e for exp2-domain softmax). r20 version.
// ---------------------------------------------------------------------------
__global__ __launch_bounds__(256) void prep_w(
    const float* __restrict__ Wq, const float* __restrict__ Wk,
    const float* __restrict__ Wv, unsigned short* __restrict__ Wt)
{
  const int mtx = blockIdx.x >> 4;
  const int k0  = (blockIdx.x & 15) * 64;
  const float* W = (mtx == 0) ? Wq : ((mtx == 1) ? Wk : Wv);
  const float scale = (mtx == 0) ? QSCALE : 1.0f;
  __shared__ float Ws[64][65];
  const int t = threadIdx.x;
#pragma unroll
  for (int j = 0; j < 4; ++j) {
    int r = (t >> 4) + 16 * j;
    int c = (t & 15) * 4;
    union { float4 f4; float f[4]; } uv;
    uv.f4 = *(const float4*)&W[(size_t)(k0 + r) * 64 + c];
#pragma unroll
    for (int jj = 0; jj < 4; ++jj) Ws[c + jj][r] = uv.f[jj] * scale;
  }
  __syncthreads();
#pragma unroll
  for (int q = 0; q < 2; ++q) {
    int g_ = t + 256 * q;
    int d  = g_ >> 3;
    int ko = (g_ & 7) * 8;
    union { unsigned short u[8]; u32x4 v; } pk;
#pragma unroll
    for (int jj = 0; jj < 8; ++jj) pk.u[jj] = f2bf(Ws[d][ko + jj]);
    *(u32x4*)&Wt[((size_t)mtx * 64 + d) * C_DIM + k0 + ko] = pk.v;
  }
}

// ---------------------------------------------------------------------------
// qkv_proj_mfma v5: BK=128, 64 rows/block, 256 blocks, single 64 KB buffer.
// r12's proven load-in-flight pattern at half the drain count:
//   per step: ds_write staged regs -> barrier (lgkm only) ->
//             issue NEXT step's X+W global loads into regs ->
//             compute 48 MFMA/wave (covers part of the load latency) ->
//             barrier (drains next-step loads; exposed ~= lat - compute).
// 8 HBM-scale drains (vs r12's 16), 2x compute per drain, W L2 traffic
// halved (98 MB). VGPR ~200 is free: 64 KB LDS caps at 8 waves/CU anyway.
// ---------------------------------------------------------------------------
__global__ __launch_bounds__(256) void qkv_proj_mfma(
    const float* __restrict__ x,
    const unsigned short* __restrict__ Wt,
    const float* __restrict__ bq, const float* __restrict__ bk, const float* __restrict__ bv,
    unsigned short* __restrict__ Qb, unsigned short* __restrict__ Kb,
    unsigned short* __restrict__ VTb)
{
  __shared__ __align__(16) char SM[65536];   // Xs [0,16K): 64r x 256B; Ws [16K,64K): 192r x 256B
  char* Xs = SM;
  char* Wsl = SM + 16384;

  const int tid = threadIdx.x;
  const int wv = tid >> 6, lane = tid & 63, g = lane >> 4, ln15 = lane & 15;
  const size_t m0 = (size_t)blockIdx.x * 64;

  f32x4 acc[4][3];   // [mt][j]
#pragma unroll
  for (int mt = 0; mt < 4; ++mt)
#pragma unroll
    for (int j = 0; j < 3; ++j) acc[mt][j] = (f32x4){0.f, 0.f, 0.f, 0.f};

  float4 xr_[8];     // staged X regs (64 rows x 128 floats / 256 thr)
  u32x4  wr_[12];    // staged W regs (192 rows x 256 B / 256 thr)

  auto issueX = [&](int bk2) {
    if (bk2 >= 8) return;
#pragma unroll
    for (int q = 0; q < 8; ++q) {
      int g_ = tid + 256 * q;             // float4 granule 0..2047
      int r = g_ >> 5, c4 = (g_ & 31) * 4;
      xr_[q] = *(const float4*)&x[(m0 + r) * C_DIM + bk2 * 128 + c4];
    }
  };
  auto issueW = [&](int bk2) {
    if (bk2 >= 8) return;
#pragma unroll
    for (int q = 0; q < 12; ++q) {
      int g2 = tid + 256 * q;             // 16B granule 0..3071
      int row = g2 >> 4, bo8 = (g2 & 15) * 8;   // row 0..191, short-offset 0..120
      wr_[q] = *(const u32x4*)&Wt[(size_t)row * C_DIM + bk2 * 128 + bo8];
    }
  };
  auto writeXb = [&]() {
#pragma unroll
    for (int q = 0; q < 8; ++q) {
      int g_ = tid + 256 * q;
      int r = g_ >> 5, c4 = (g_ & 31) * 4;
      const float* f = (const float*)&xr_[q];
      union { unsigned short u[4]; unsigned long long ll; } pk;
#pragma unroll
      for (int jj = 0; jj < 4; ++jj) pk.u[jj] = f2bf(f[jj]);
      *(unsigned long long*)(Xs + r * 256 + ((c4 * 2) ^ ((r & 7) << 4))) = pk.ll;
    }
  };
  auto writeWb = [&]() {
#pragma unroll
    for (int q = 0; q < 12; ++q) {
      int g2 = tid + 256 * q;
      int row = g2 >> 4, bo = (g2 & 15) * 16;
      *(u32x4*)(Wsl + row * 256 + (bo ^ ((row & 7) << 4))) = wr_[q];
    }
  };
  auto compute = [&]() {
#pragma unroll
    for (int kc = 0; kc < 4; ++kc) {
      bf16x8 a[4];
#pragma unroll
      for (int mt = 0; mt < 4; ++mt) {
        int xr2 = mt * 16 + ln15;
        a[mt] = *(const bf16x8*)(Xs + xr2 * 256 + ((kc * 64 + g * 16) ^ ((xr2 & 7) << 4)));
      }
#pragma unroll
      for (int j = 0; j < 3; ++j) {
        int row = (wv * 3 + j) * 16 + ln15;   // n index 0..191
        bf16x8 bb = *(const bf16x8*)(Wsl + row * 256 + ((kc * 64 + g * 16) ^ ((row & 7) << 4)));
#pragma unroll
        for (int mt = 0; mt < 4; ++mt)
          acc[mt][j] = mfma16(a[mt], bb, acc[mt][j]);
      }
    }
  };

  issueX(0); issueW(0);
  for (int bk2 = 0; bk2 < 8; ++bk2) {
    writeXb(); writeWb();
    __syncthreads();                 // LDS ready; no globals outstanding
    issueX(bk2 + 1); issueW(bk2 + 1);// next step's loads fly under compute
    compute();
    __syncthreads();                 // drains next-step loads + LDS reads done
  }

  // epilogue: Q/K direct; V -> LDS transpose tile (aliases SM) -> VTb
  unsigned short* VTs = (unsigned short*)SM;   // 64 d x 72 stride (9 KB < 16 KB)
#pragma unroll
  for (int j = 0; j < 3; ++j) {
    int ntg = wv * 3 + j;
    int mtx = ntg >> 2, nc = (ntg & 3) * 16;
    if (mtx < 2) {
      const float* bias = (mtx == 0) ? bq : bk;
      unsigned short* Out = (mtx == 0) ? Qb : Kb;
      float bvv = bias[nc + ln15] * ((mtx == 0) ? QSCALE : 1.0f);
#pragma unroll
      for (int mt = 0; mt < 4; ++mt)
#pragma unroll
        for (int i = 0; i < 4; ++i)
          Out[(m0 + mt * 16 + 4 * g + i) * 64 + nc + ln15] = f2bf(acc[mt][j][i] + bvv);
    } else {
      float bvv = bv[nc + ln15];
#pragma unroll
      for (int mt = 0; mt < 4; ++mt)
#pragma unroll
        for (int i = 0; i < 4; ++i)
          VTs[(nc + ln15) * 72 + mt * 16 + 4 * g + i] = f2bf(acc[mt][j][i] + bvv);
    }
  }
  __syncthreads();
  {
    int d = tid >> 2, t8 = (tid & 3) * 16;
    u32x4 v0 = *(const u32x4*)&VTs[d * 72 + t8];
    u32x4 v1 = *(const u32x4*)&VTs[d * 72 + t8 + 8];
    size_t b = m0 >> 11, tloc = m0 & 2047;
    *(u32x4*)&VTb[(b * 64 + d) * T_DIM + tloc + t8] = v0;
    *(u32x4*)&VTb[(b * 64 + d) * T_DIM + tloc + t8 + 8] = v1;
  }
}

// ---------------------------------------------------------------------------
// attn_flash: round-15 version EXACT (best measured). Unchanged.
// ---------------------------------------------------------------------------
__global__ __launch_bounds__(256, 2) void attn_flash(
    const unsigned short* __restrict__ Qb,   // [B*T][64] (pre-scaled QSCALE)
    const unsigned short* __restrict__ Kb,   // [B*T][64]
    const unsigned short* __restrict__ VTb,  // [B][64][T]
    float* __restrict__ out)                 // [B*T][64] f32
{
  __shared__ __align__(16) short Ps[4][2 * 16 * 64];
  __shared__ __align__(16) float Zs[3][2][16 * 68];
  __shared__ float Ml[3][2][16][2];

  const int tid  = threadIdx.x;
  const int wv   = tid >> 6;
  const int lane = tid & 63;
  const int g    = lane >> 4;
  const int ln15 = lane & 15;

  const int qt = 63 - (blockIdx.x >> 3);
  const int b  = blockIdx.x & 7;
  const int r0 = qt * 32;
  const int ntiles = (qt >> 1) + 1;

  const size_t bT = (size_t)b * T_DIM;

  bf16x8 qa[2][2];
#pragma unroll
  for (int mt = 0; mt < 2; ++mt) {
    const unsigned short* qp = Qb + (bT + r0 + mt * 16 + ln15) * 64 + g * 8;
    qa[mt][0] = *(const bf16x8*)qp;
    qa[mt][1] = *(const bf16x8*)(qp + 32);
  }

  f32x4 acc[2][4];
#pragma unroll
  for (int mt = 0; mt < 2; ++mt)
#pragma unroll
    for (int dt = 0; dt < 4; ++dt) acc[mt][dt] = (f32x4){0.f, 0.f, 0.f, 0.f};
  float m_[2], l_[2];
#pragma unroll
  for (int mt = 0; mt < 2; ++mt) { m_[mt] = NEG_BIG; l_[mt] = 0.f; }

  char* myP = (char*)Ps[wv];

  for (int it = wv; it < ntiles; it += 4) {
    const int s0 = it * 64;
    bf16x8 kf[4][2];
#pragma unroll
    for (int nt = 0; nt < 4; ++nt) {
      const unsigned short* kp = Kb + (bT + s0 + nt * 16 + ln15) * 64 + g * 8;
      kf[nt][0] = *(const bf16x8*)kp;
      kf[nt][1] = *(const bf16x8*)(kp + 32);
    }
    bf16x8 vf[4][2];
#pragma unroll
    for (int dt = 0; dt < 4; ++dt) {
      const unsigned short* vp = VTb + ((size_t)b * 64 + dt * 16 + ln15) * T_DIM + s0 + g * 8;
      vf[dt][0] = *(const bf16x8*)vp;
      vf[dt][1] = *(const bf16x8*)(vp + 32);
    }
    f32x4 st[2][4];
    __builtin_amdgcn_s_setprio(1);
#pragma unroll
    for (int mt = 0; mt < 2; ++mt)
#pragma unroll
      for (int nt = 0; nt < 4; ++nt) {
        f32x4 a = (f32x4){0.f, 0.f, 0.f, 0.f};
        a = mfma16(kf[nt][0], qa[mt][0], a);
        a = mfma16(kf[nt][1], qa[mt][1], a);
        st[mt][nt] = a;
      }
    __builtin_amdgcn_s_setprio(0);
    if (s0 + 63 > r0) {
#pragma unroll
      for (int mt = 0; mt < 2; ++mt) {
        const int qg = r0 + mt * 16 + ln15;
#pragma unroll
        for (int nt = 0; nt < 4; ++nt) {
          const int kvb = s0 + nt * 16 + 4 * g;
#pragma unroll
          for (int i = 0; i < 4; ++i)
            if (kvb + i > qg) st[mt][nt][i] = NEG_BIG;
        }
      }
    }
#pragma unroll
    for (int mt = 0; mt < 2; ++mt) {
      f32x4 t4;
#pragma unroll
      for (int i = 0; i < 4; ++i)
        t4[i] = fmaxf(fmaxf(st[mt][0][i], st[mt][1][i]), fmaxf(st[mt][2][i], st[mt][3][i]));
      float mx = fmaxf(fmaxf(t4[0], t4[1]), fmaxf(t4[2], t4[3]));
      if (!__all((int)(mx <= m_[mt] + 8.0f))) {
        mx = fmaxf(mx, __shfl_xor(mx, 16));
        mx = fmaxf(mx, __shfl_xor(mx, 32));
        const float mn = fmaxf(m_[mt], mx);
        const float corr = exp2f(m_[mt] - mn);
        m_[mt] = mn;
        l_[mt] *= corr;
#pragma unroll
        for (int dt = 0; dt < 4; ++dt)
#pragma unroll
          for (int i = 0; i < 4; ++i)
            acc[mt][dt][i] *= corr;
      }
#pragma unroll
      for (int nt = 0; nt < 4; ++nt)
#pragma unroll
        for (int i = 0; i < 4; ++i)
          st[mt][nt][i] = exp2f(st[mt][nt][i] - m_[mt]);
      float ps = 0.f;
#pragma unroll
      for (int nt = 0; nt < 4; ++nt)
        ps += (st[mt][nt][0] + st[mt][nt][1]) + (st[mt][nt][2] + st[mt][nt][3]);
      l_[mt] += ps;
#pragma unroll
      for (int nt = 0; nt < 4; ++nt) {
        unsigned int lo_ = (unsigned int)f2bf(st[mt][nt][0]) | ((unsigned int)f2bf(st[mt][nt][1]) << 16);
        unsigned int hi_ = (unsigned int)f2bf(st[mt][nt][2]) | ((unsigned int)f2bf(st[mt][nt][3]) << 16);
        *(unsigned long long*)(myP + mt * 2048 + ln15 * 128 +
                               ((nt * 32 + g * 8) ^ ((ln15 & 7) << 4))) =
            ((unsigned long long)hi_ << 32) | lo_;
      }
    }
    bf16x8 pb[2][2];
#pragma unroll
    for (int mt = 0; mt < 2; ++mt)
#pragma unroll
      for (int kc = 0; kc < 2; ++kc)
        pb[mt][kc] = *(const bf16x8*)(myP + mt * 2048 + ln15 * 128 +
                                      ((kc * 64 + g * 16) ^ ((ln15 & 7) << 4)));
    __builtin_amdgcn_s_setprio(1);
#pragma unroll
    for (int mt = 0; mt < 2; ++mt)
#pragma unroll
      for (int dt = 0; dt < 4; ++dt) {
        acc[mt][dt] = mfma16(vf[dt][0], pb[mt][0], acc[mt][dt]);
        acc[mt][dt] = mfma16(vf[dt][1], pb[mt][1], acc[mt][dt]);
      }
    __builtin_amdgcn_s_setprio(0);
  }

#pragma unroll
  for (int mt = 0; mt < 2; ++mt) {
    l_[mt] += __shfl_xor(l_[mt], 16);
    l_[mt] += __shfl_xor(l_[mt], 32);
  }

  if (wv > 0) {
#pragma unroll
    for (int mt = 0; mt < 2; ++mt) {
#pragma unroll
      for (int dt = 0; dt < 4; ++dt)
        *(f32x4*)&Zs[wv - 1][mt][ln15 * 68 + dt * 16 + 4 * g] = acc[mt][dt];
      if (g == 0) {
        Ml[wv - 1][mt][ln15][0] = m_[mt];
        Ml[wv - 1][mt][ln15][1] = l_[mt];
      }
    }
  }
  __syncthreads();
  if (wv == 0) {
#pragma unroll
    for (int mt = 0; mt < 2; ++mt) {
      float mm = m_[mt];
#pragma unroll
      for (int w = 0; w < 3; ++w) mm = fmaxf(mm, Ml[w][mt][ln15][0]);
      const float e0 = exp2f(m_[mt] - mm);
      float lsum = l_[mt] * e0;
      float ew[3];
#pragma unroll
      for (int w = 0; w < 3; ++w) {
        ew[w] = exp2f(Ml[w][mt][ln15][0] - mm);
        lsum += Ml[w][mt][ln15][1] * ew[w];
      }
      const float inv = 1.0f / lsum;
      float* ob = out + (bT + r0 + mt * 16 + ln15) * 64;
#pragma unroll
      for (int dt = 0; dt < 4; ++dt) {
        f32x4 z;
#pragma unroll
        for (int i = 0; i < 4; ++i) {
          float zz = acc[mt][dt][i] * e0;
#pragma unroll
          for (int w = 0; w < 3; ++w)
            zz += Zs[w][mt][ln15 * 68 + dt * 16 + 4 * g + i] * ew[w];
          z[i] = zz * inv;
        }
        *(f32x4*)&ob[dt * 16 + 4 * g] = z;
      }
    }
  }
}

// ---------------------------------------------------------------------------
extern "C" void kernel_launch(void* const* d_in, const int* in_sizes, int n_in,
                              void* d_out, int out_size, void* d_ws, size_t ws_size,
                              hipStream_t stream)
{
  const float* x  = (const float*)d_in[0];
  const float* Wq = (const float*)d_in[1];
  const float* bq = (const float*)d_in[2];
  const float* Wk = (const float*)d_in[3];
  const float* bk = (const float*)d_in[4];
  const float* Wv = (const float*)d_in[5];
  const float* bv = (const float*)d_in[6];
  float* out = (float*)d_out;

  char* ws = (char*)d_ws;
  unsigned short* Wt  = (unsigned short*)(ws);                      // 384 KB
  unsigned short* Qb  = (unsigned short*)(ws + (1u << 19));         // 2 MB
  unsigned short* Kb  = (unsigned short*)(ws + (1u << 19) + (1u << 21));
  unsigned short* VTb = (unsigned short*)(ws + (1u << 19) + (2u << 21));

  prep_w<<<48, 256, 0, stream>>>(Wq, Wk, Wv, Wt);
  qkv_proj_mfma<<<256, 256, 0, stream>>>(x, Wt, bq, bk, bv, Qb, Kb, VTb);
  attn_flash<<<512, 256, 0, stream>>>(Qb, Kb, VTb, out);
}